// Round 9
// baseline (15.167 us; speedup 1.0000x reference)
//
#include <hip/hip_runtime.h>

#define D_EMB   64
#define D_HID   128
#define NUM_EL  118
#define CHUNK   1024     // atoms per gather-block (4/thread as one int4)
#define NBINS   16
#define K2_GRID 2048     // full-occupancy grid for the streaming kernel

// ---------------------------------------------------------------------------
// Kernel 1: per-element energy table (118 blocks; 2 threads per hidden unit)
// + zero energy[B]. Tiny and latency-bound; keeps the kernel boundary that
// carries the Etab dependency.
// ---------------------------------------------------------------------------
__global__ __launch_bounds__(256)
void mace_etab_kernel(const float* __restrict__ embed,
                      const float* __restrict__ W1, const float* __restrict__ b1,
                      const float* __restrict__ W2, const float* __restrict__ b2,
                      const float* __restrict__ W3, const float* __restrict__ b3,
                      float* __restrict__ Etab, float* __restrict__ energy, int B) {
    __shared__ float h[D_EMB];
    __shared__ float x1[D_HID];
    __shared__ float part[D_HID];
    __shared__ float wsum[2];
    const int t  = threadIdx.x;
    const int j  = t & 127;
    const int hf = t >> 7;
    const int zz = blockIdx.x;

    const int eidx = zz * 256 + t;          // blocks 0..3 cover B=1024
    if (eidx < B) energy[eidx] = 0.f;

    if (t < D_EMB) h[t] = embed[zz * D_EMB + t];
    __syncthreads();

    // layer 1: k split 32/32 across hf
    {
        const int k0 = hf * 32;
        float a0 = 0.f, a1 = 0.f, a2 = 0.f, a3 = 0.f;
        #pragma unroll
        for (int k = 0; k < 32; k += 4) {
            a0 = fmaf(h[k0 + k + 0], W1[(k0 + k + 0) * D_HID + j], a0);
            a1 = fmaf(h[k0 + k + 1], W1[(k0 + k + 1) * D_HID + j], a1);
            a2 = fmaf(h[k0 + k + 2], W1[(k0 + k + 2) * D_HID + j], a2);
            a3 = fmaf(h[k0 + k + 3], W1[(k0 + k + 3) * D_HID + j], a3);
        }
        const float p = (a0 + a1) + (a2 + a3);
        if (hf == 1) part[j] = p;
        __syncthreads();
        if (hf == 0) {
            const float acc = b1[j] + p + part[j];
            x1[j] = acc / (1.0f + expf(-acc));
        }
        __syncthreads();
    }
    // layer 2 + dot(W3): k split 64/64 across hf
    float r = 0.f;
    {
        const int k0 = hf * 64;
        float a0 = 0.f, a1 = 0.f, a2 = 0.f, a3 = 0.f;
        #pragma unroll
        for (int k = 0; k < 64; k += 4) {
            a0 = fmaf(x1[k0 + k + 0], W2[(k0 + k + 0) * D_HID + j], a0);
            a1 = fmaf(x1[k0 + k + 1], W2[(k0 + k + 1) * D_HID + j], a1);
            a2 = fmaf(x1[k0 + k + 2], W2[(k0 + k + 2) * D_HID + j], a2);
            a3 = fmaf(x1[k0 + k + 3], W2[(k0 + k + 3) * D_HID + j], a3);
        }
        const float p = (a0 + a1) + (a2 + a3);
        if (hf == 1) part[j] = p;
        __syncthreads();
        if (hf == 0) {
            const float acc2 = b2[j] + p + part[j];
            const float s2 = acc2 / (1.0f + expf(-acc2));
            r = s2 * W3[j];
        }
    }
    #pragma unroll
    for (int off = 32; off > 0; off >>= 1)
        r += __shfl_down(r, off, 64);
    if (hf == 0 && (t & 63) == 0) wsum[t >> 6] = r;
    __syncthreads();
    if (t == 0) Etab[zz] = wsum[0] + wsum[1] + b3[0];
}

// ---------------------------------------------------------------------------
// Kernel 2: full-occupancy streaming pass (2048 blocks).
//   all blocks      : grid-strided float4 zero of forces (12 MB)
//   blocks < nchunk : one int4 of z + batch (coalesced), register
//                     run-accumulation over sorted ids, flush to 16 LDS
//                     bins, <=NBINS global atomics -> energy
// ---------------------------------------------------------------------------
__global__ __launch_bounds__(256)
void mace_sum_kernel(const int* __restrict__ z,
                     const int* __restrict__ batch,
                     const float* __restrict__ EtabG,
                     float* __restrict__ energy,
                     float4* __restrict__ forces4,
                     int n, int nf4, int nchunk) {
    __shared__ float etab_s[NUM_EL];
    __shared__ float bins[NBINS];
    __shared__ int   base_s;
    const int t   = threadIdx.x;
    const int bid = blockIdx.x;

    // issue gather loads first so they overlap the zeroing stores
    const int n4 = n >> 2;
    int4 zv = make_int4(0, 0, 0, 0), bv = make_int4(0, 0, 0, 0);
    const bool gather = (bid < nchunk);
    bool valid = false;
    if (gather) {
        const int i4 = (bid << 8) + t;
        valid = (i4 < n4);
        if (valid) {
            zv = ((const int4*)z)[i4];
            bv = ((const int4*)batch)[i4];
        }
        if (t < NUM_EL) etab_s[t] = EtabG[t];
        if (t < NBINS)  bins[t] = 0.f;
        if (t == 0)     base_s = bv.x;      // batch[chunk base]
    }

    // zero forces: ~1.4 float4 stores per thread at full grid
    {
        const float4 z4f = make_float4(0.f, 0.f, 0.f, 0.f);
        for (int i = bid * 256 + t; i < nf4; i += K2_GRID * 256)
            forces4[i] = z4f;
    }

    if (!gather) return;
    __syncthreads();
    const int base = base_s;

    if (valid) {
        const float e0 = etab_s[zv.x], e1 = etab_s[zv.y];
        const float e2 = etab_s[zv.z], e3 = etab_s[zv.w];
        float acc = e0;
        int   bc  = bv.x;
        #define FLUSH()                                                     \
            do {                                                            \
                const int bin = bc - base;                                  \
                if (bin < NBINS) atomicAdd(&bins[bin], acc);                \
                else             atomicAdd(&energy[bc], acc);               \
            } while (0)
        if (bv.y == bc) acc += e1; else { FLUSH(); bc = bv.y; acc = e1; }
        if (bv.z == bc) acc += e2; else { FLUSH(); bc = bv.z; acc = e2; }
        if (bv.w == bc) acc += e3; else { FLUSH(); bc = bv.w; acc = e3; }
        FLUSH();
        #undef FLUSH
    }

    // scalar-tail insurance for n % 4 != 0 (not hit at n = 1e6)
    if (bid == nchunk - 1 && t == 0) {
        for (int i = n4 << 2; i < n; ++i)
            atomicAdd(&energy[batch[i]], etab_s[z[i]]);
    }

    __syncthreads();
    if (t < NBINS) {
        const float v = bins[t];
        // v != 0 implies molecule (base+t) really occurred -> index in-bounds;
        // skipping a zero-valued partial is also correct (adds nothing).
        if (v != 0.f) atomicAdd(&energy[base + t], v);
    }
}

extern "C" void kernel_launch(void* const* d_in, const int* in_sizes, int n_in,
                              void* d_out, int out_size, void* d_ws, size_t ws_size,
                              hipStream_t stream) {
    // 0 positions, 1 embed, 2 W1, 3 b1, 4 W2, 5 b2, 6 W3, 7 b3,
    // 8 atomic_numbers, 9 batch
    const float* embed = (const float*)d_in[1];
    const float* W1    = (const float*)d_in[2];
    const float* b1    = (const float*)d_in[3];
    const float* W2    = (const float*)d_in[4];
    const float* b2    = (const float*)d_in[5];
    const float* W3    = (const float*)d_in[6];
    const float* b3    = (const float*)d_in[7];
    const int*   zp    = (const int*)d_in[8];
    const int*   batch = (const int*)d_in[9];
    const int    n     = in_sizes[8];                // 1,000,000

    const int B      = out_size - 3 * n;             // 1024
    const int nf4    = (3 * n) / 4;                  // 750,000
    const int nchunk = (n + CHUNK - 1) / CHUNK;      // 977

    float*  energy  = (float*)d_out;                 // [B]
    float4* forces4 = (float4*)((float*)d_out + B);  // [3N], 16B-aligned
    float*  Etab    = (float*)d_ws;                  // 128 f32 scratch

    mace_etab_kernel<<<NUM_EL, 256, 0, stream>>>(embed, W1, b1, W2, b2, W3, b3,
                                                 Etab, energy, B);
    mace_sum_kernel<<<K2_GRID, 256, 0, stream>>>(zp, batch, Etab, energy,
                                                 forces4, n, nf4, nchunk);
}

// Round 10
// 13.788 us; speedup vs baseline: 1.1000x; 1.1000x over previous
//
#include <hip/hip_runtime.h>

#define D_EMB   64
#define D_HID   128
#define NUM_EL  118
#define HPAD    120              // padded hist row (u16 elements)
#define NSLOT   4                // molecules tracked per chunk (avg seg ~977)
#define CHUNK   1024             // atoms per chunk block
#define NCHUNK_BLOCKS(n) (((n) + CHUNK - 1) / CHUNK)

// ---------------------------------------------------------------------------
// Kernel 1: single streaming pass + MLP. Grid = 118 + nchunk blocks.
//   blocks [0, 118)           : MLP -> Etab[z]  (FIRST: serial-latency blocks
//                               dispatch earliest and hide under streaming)
//   blocks [118, 118+nchunk)  : chunk blocks — int4 z/batch read, LDS-neighbor
//                               diff-pass -> starts[], DS-atomic 4x118 LDS
//                               histogram -> u16 global rows, chunkbase[]
//   all blocks                : grid-strided float4 zero of forces (12 MB)
// ---------------------------------------------------------------------------
__global__ __launch_bounds__(256)
void mace_prep_kernel(const float* __restrict__ embed,
                      const float* __restrict__ W1, const float* __restrict__ b1,
                      const float* __restrict__ W2, const float* __restrict__ b2,
                      const float* __restrict__ W3, const float* __restrict__ b3,
                      const int* __restrict__ z,
                      const int* __restrict__ batch,
                      float* __restrict__ Etab,
                      int* __restrict__ starts,
                      int* __restrict__ chunkbase,
                      unsigned short* __restrict__ hist16,
                      float4* __restrict__ forces4,
                      int nf4, int n, int B, int nblocks) {
    const int t   = threadIdx.x;
    const int bid = blockIdx.x;

    // ---- force zero (all blocks) ----
    {
        const float4 z4f = make_float4(0.f, 0.f, 0.f, 0.f);
        const int stride = nblocks * 256;
        for (int i = bid * 256 + t; i < nf4; i += stride)
            forces4[i] = z4f;
    }

    if (bid < NUM_EL) {
        // ================= MLP block =================
        __shared__ float h[D_EMB];
        __shared__ float x1[D_HID];
        __shared__ float part[D_HID];
        __shared__ float wsum[2];
        const int zz = bid;
        const int j  = t & 127;
        const int hf = t >> 7;

        // tail of starts: b in (batch[n-1], B]  (block 0 only)
        if (bid == 0 && t == 0) {
            const int last = batch[n - 1];
            for (int b = last + 1; b <= B; ++b) starts[b] = n;
        }

        if (t < D_EMB) h[t] = embed[zz * D_EMB + t];
        __syncthreads();

        // layer 1: k split 32/32 across hf
        {
            const int k0 = hf * 32;
            float a0 = 0.f, a1 = 0.f, a2 = 0.f, a3 = 0.f;
            #pragma unroll
            for (int k = 0; k < 32; k += 4) {
                a0 = fmaf(h[k0 + k + 0], W1[(k0 + k + 0) * D_HID + j], a0);
                a1 = fmaf(h[k0 + k + 1], W1[(k0 + k + 1) * D_HID + j], a1);
                a2 = fmaf(h[k0 + k + 2], W1[(k0 + k + 2) * D_HID + j], a2);
                a3 = fmaf(h[k0 + k + 3], W1[(k0 + k + 3) * D_HID + j], a3);
            }
            const float p = (a0 + a1) + (a2 + a3);
            if (hf == 1) part[j] = p;
            __syncthreads();
            if (hf == 0) {
                const float acc = b1[j] + p + part[j];
                x1[j] = acc / (1.0f + expf(-acc));
            }
            __syncthreads();
        }
        // layer 2 + dot(W3): k split 64/64 across hf
        float r = 0.f;
        {
            const int k0 = hf * 64;
            float a0 = 0.f, a1 = 0.f, a2 = 0.f, a3 = 0.f;
            #pragma unroll
            for (int k = 0; k < 64; k += 4) {
                a0 = fmaf(x1[k0 + k + 0], W2[(k0 + k + 0) * D_HID + j], a0);
                a1 = fmaf(x1[k0 + k + 1], W2[(k0 + k + 1) * D_HID + j], a1);
                a2 = fmaf(x1[k0 + k + 2], W2[(k0 + k + 2) * D_HID + j], a2);
                a3 = fmaf(x1[k0 + k + 3], W2[(k0 + k + 3) * D_HID + j], a3);
            }
            const float p = (a0 + a1) + (a2 + a3);
            if (hf == 1) part[j] = p;
            __syncthreads();
            if (hf == 0) {
                const float acc2 = b2[j] + p + part[j];
                const float s2 = acc2 / (1.0f + expf(-acc2));
                r = s2 * W3[j];
            }
        }
        #pragma unroll
        for (int off = 32; off > 0; off >>= 1)
            r += __shfl_down(r, off, 64);
        if (hf == 0 && (t & 63) == 0) wsum[t >> 6] = r;
        __syncthreads();
        if (t == 0) Etab[zz] = wsum[0] + wsum[1] + b3[0];

    } else {
        // ================= chunk block =================
        __shared__ unsigned int shist[NSLOT * HPAD];
        __shared__ int lastw[256];      // v.w per thread for neighbor exchange
        __shared__ int base_s;

        const int c = bid - NUM_EL;
        for (int i = t; i < NSLOT * HPAD; i += 256) shist[i] = 0u;

        const int n4 = n >> 2;
        const int i4 = (c << 8) + t;
        const bool valid = (i4 < n4);
        int4 zv = make_int4(0, 0, 0, 0), bv = make_int4(0, 0, 0, 0);
        if (valid) {
            zv = ((const int4*)z)[i4];
            bv = ((const int4*)batch)[i4];
        }
        if (t == 0) base_s = bv.x;
        lastw[t] = bv.w;
        __syncthreads();
        const int base = base_s;

        if (valid) {
            const int idx = i4 << 2;

            // histogram (batch sorted => bv.* - base in [0, ...))
            const int s0 = bv.x - base, s1 = bv.y - base;
            const int s2 = bv.z - base, s3 = bv.w - base;
            if (s0 < NSLOT) atomicAdd(&shist[s0 * HPAD + zv.x], 1u);
            if (s1 < NSLOT) atomicAdd(&shist[s1 * HPAD + zv.y], 1u);
            if (s2 < NSLOT) atomicAdd(&shist[s2 * HPAD + zv.z], 1u);
            if (s3 < NSLOT) atomicAdd(&shist[s3 * HPAD + zv.w], 1u);

            // diff-pass -> starts (boundary (c0,c1] at position i => starts)
            int prev;
            if (t > 0)            prev = lastw[t - 1];
            else if (c > 0)       prev = batch[idx - 1];   // one scalar/block
            else                  prev = -1;               // head: b<=batch[0] -> 0
            if (prev != bv.x) { const int lo = (prev < 0) ? 0 : prev + 1;
                                for (int b = lo; b <= bv.x; ++b) starts[b] = (prev < 0) ? 0 : idx; }
            if (bv.x != bv.y) { for (int b = bv.x + 1; b <= bv.y; ++b) starts[b] = idx + 1; }
            if (bv.y != bv.z) { for (int b = bv.y + 1; b <= bv.z; ++b) starts[b] = idx + 2; }
            if (bv.z != bv.w) { for (int b = bv.z + 1; b <= bv.w; ++b) starts[b] = idx + 3; }
        }
        if (t == 0) chunkbase[c] = base;
        __syncthreads();

        // flush hist row as u16 (coalesced 2B stores)
        unsigned short* __restrict__ hrow = hist16 + (size_t)c * (NSLOT * HPAD);
        for (int i = t; i < NSLOT * HPAD; i += 256)
            hrow[i] = (unsigned short)shist[i];
    }
}

// ---------------------------------------------------------------------------
// Kernel 2: one 128-thread block per molecule.
// energy[b] = sum over overlapping chunks c of dot(hist16[c][b-base], Etab).
// Bounds from starts[] (2 scalar loads); slot overflow (impossible for this
// data) falls back to a raw z scan of the chunk/segment intersection.
// ---------------------------------------------------------------------------
__global__ __launch_bounds__(128)
void mace_energy_kernel(const int* __restrict__ z,
                        const int* __restrict__ starts,
                        const int* __restrict__ chunkbase,
                        const unsigned short* __restrict__ hist16,
                        const float* __restrict__ EtabG,
                        float* __restrict__ energy, int n) {
    __shared__ float etab_s[NUM_EL];
    __shared__ float wsum[2];
    const int b = blockIdx.x;
    const int t = threadIdx.x;

    if (t < NUM_EL) etab_s[t] = EtabG[t];
    const int start = starts[b];
    const int end   = starts[b + 1];
    __syncthreads();

    float acc = 0.f;
    if (end > start) {
        const int c0 = start >> 10;
        const int c1 = (end - 1) >> 10;
        for (int c = c0; c <= c1; ++c) {
            const int slot = b - chunkbase[c];
            if (slot < NSLOT) {
                if (t < NUM_EL) {
                    const unsigned short cnt =
                        hist16[((size_t)c * NSLOT + slot) * HPAD + t];
                    acc = fmaf((float)cnt, etab_s[t], acc);
                }
            } else {
                // overflow fallback: raw z over the chunk/segment intersection
                const int lo = max(start, c << 10);
                const int hi = min(end, (c + 1) << 10);
                for (int i = lo + t; i < hi; i += 128)
                    acc += etab_s[z[i]];
            }
        }
    }

    #pragma unroll
    for (int off = 32; off > 0; off >>= 1)
        acc += __shfl_down(acc, off, 64);
    if ((t & 63) == 0) wsum[t >> 6] = acc;
    __syncthreads();
    if (t == 0) energy[b] = wsum[0] + wsum[1];
}

extern "C" void kernel_launch(void* const* d_in, const int* in_sizes, int n_in,
                              void* d_out, int out_size, void* d_ws, size_t ws_size,
                              hipStream_t stream) {
    // 0 positions, 1 embed, 2 W1, 3 b1, 4 W2, 5 b2, 6 W3, 7 b3,
    // 8 atomic_numbers, 9 batch
    const float* embed = (const float*)d_in[1];
    const float* W1    = (const float*)d_in[2];
    const float* b1    = (const float*)d_in[3];
    const float* W2    = (const float*)d_in[4];
    const float* b2    = (const float*)d_in[5];
    const float* W3    = (const float*)d_in[6];
    const float* b3    = (const float*)d_in[7];
    const int*   zp    = (const int*)d_in[8];
    const int*   batch = (const int*)d_in[9];
    const int    n     = in_sizes[8];                  // 1,000,000

    const int B       = out_size - 3 * n;              // 1024
    const int nf4     = (3 * n) / 4;                   // 750,000
    const int nchunk  = NCHUNK_BLOCKS(n);              // 977
    const int nblocks = NUM_EL + nchunk;               // 1095

    float*  energy  = (float*)d_out;                   // [B]
    float4* forces4 = (float4*)((float*)d_out + B);    // [3N], 16B-aligned

    char* ws = (char*)d_ws;
    float*          Etab      = (float*)(ws);          // 128 f32
    int*            starts    = (int*)(ws + 512);      // B+1 ints
    int*            chunkbase = (int*)(ws + 8192);     // nchunk ints
    unsigned short* hist16    = (unsigned short*)(ws + 16384); // nchunk*480 u16

    mace_prep_kernel<<<nblocks, 256, 0, stream>>>(embed, W1, b1, W2, b2, W3, b3,
                                                  zp, batch, Etab, starts,
                                                  chunkbase, hist16, forces4,
                                                  nf4, n, B, nblocks);
    mace_energy_kernel<<<B, 128, 0, stream>>>(zp, starts, chunkbase, hist16,
                                              Etab, energy, n);
}